// Round 6
// baseline (334.436 us; speedup 1.0000x reference)
//
#include <hip/hip_runtime.h>

constexpr int N    = 8192;
constexpr int NPG  = 512;   // nodes per graph
constexpr int NG   = 16;
constexpr int KNN  = 80;
constexpr int F0   = 6;
constexpr int HID  = 128;
constexpr int H6   = 768;
constexpr int RPB  = 16;    // rows per combine block
constexpr int BPGR = NPG / RPB;  // combine blocks per graph = 32
constexpr size_t SPLIT_STRIDE = (size_t)NG * HID * NPG;   // elems per split plane

typedef _Float16 half8 __attribute__((ext_vector_type(8)));
typedef float    f32x4 __attribute__((ext_vector_type(4)));

__device__ __forceinline__ float leaky(float v) { return v > 0.0f ? v : 0.01f * v; }

__device__ __forceinline__ int lanes_below(unsigned long long m) {
    return __builtin_amdgcn_mbcnt_hi((unsigned)(m >> 32),
           __builtin_amdgcn_mbcnt_lo((unsigned)m, 0));
}

// wave-sum of a per-lane count in [0,8] via 4 ballots (result uniform)
__device__ __forceinline__ int wave_count_sum(int c) {
    int total = 0;
    #pragma unroll
    for (int b = 0; b < 4; b++)
        total += (int)__popcll(__ballot((c >> b) & 1)) << b;
    return total;
}

// ---------------------------------------------------------------------------
// KNN, wave-per-target (see R2 notes). Also builds dense fp16 adjacency
// A[8192][512] (rows block-exclusive: zero 1KB row, scatter 80 ones).
// ---------------------------------------------------------------------------
__global__ __launch_bounds__(256) void knn_kernel(const float* __restrict__ x,
                                                  int* __restrict__ nbr,
                                                  _Float16* __restrict__ Aadj) {
    constexpr int BPG = 128;               // blocks per graph (4 targets each)
    const int tid  = threadIdx.x;
    const int lane = tid & 63;
    const int wv   = tid >> 6;
    const int base = (blockIdx.x / BPG) << 9;
    const int t    = base + (blockIdx.x & (BPG - 1)) * 4 + wv;
    const int tl   = t - base;

    __shared__ float px[512], py[512], pz[512], pw[512];
    __shared__ unsigned long long skey[4 * 128];

    {   // zero this wave's adjacency row (512 fp16 = 1024B, 16B per lane)
        const uint4 z = {0u, 0u, 0u, 0u};
        *(uint4*)(Aadj + (size_t)t * 512 + lane * 8) = z;
    }

    for (int j = tid; j < 512; j += 256) {
        const float* row = x + (size_t)(base + j) * F0;
        const float2 ra = *(const float2*)(row);
        const float2 rb = *(const float2*)(row + 2);
        px[j] = ra.x; py[j] = ra.y; pz[j] = rb.x; pw[j] = rb.y;
    }
    __syncthreads();

    const float tx = px[tl], ty = py[tl], tz = pz[tl], tw = pw[tl];
    const float sqt = tx*tx + ty*ty + tz*tz + tw*tw;

    unsigned d2m[8];
    #pragma unroll
    for (int j = 0; j < 8; j++) {
        const int node = j * 64 + lane;
        const float jx = px[node], jy = py[node], jz = pz[node], jw = pw[node];
        const float sqj = jx*jx + jy*jy + jz*jz + jw*jw;
        const float dot = tx*jx + ty*jy + tz*jz + tw*jw;
        const float d2  = sqt + sqj - 2.0f * dot;
        unsigned u = __float_as_uint(d2);
        u = (u & 0x80000000u) ? ~u : (u | 0x80000000u);   // monotonic map
        d2m[j] = (node == tl) ? 0xFFFFFFFFu : u;          // exclude self
    }

    unsigned V = 0;
    for (int b = 31; b >= 0; --b) {
        const unsigned test = V | (1u << b);
        int c = 0;
        #pragma unroll
        for (int j = 0; j < 8; j++) c += (d2m[j] < test) ? 1 : 0;
        if (wave_count_sum(c) < KNN) V = test;
    }

    int c = 0;
    #pragma unroll
    for (int j = 0; j < 8; j++) c += (d2m[j] < V) ? 1 : 0;
    const int n_lt = wave_count_sum(c);
    const int need = KNN - n_lt;

    const int woff = wv * 128;
    int cnt_total = 0, taken = 0;
    #pragma unroll
    for (int j = 0; j < 8; j++) {
        const bool lt = d2m[j] < V;
        const bool eq = d2m[j] == V;
        const unsigned long long meq = __ballot(eq);
        const bool sel = lt || (eq && (taken + lanes_below(meq)) < need);
        taken += (int)__popcll(meq);
        const unsigned long long msel = __ballot(sel);
        if (sel) {
            const int pos = cnt_total + lanes_below(msel);
            skey[woff + pos] = ((unsigned long long)d2m[j] << 32)
                             | (unsigned)(base + j * 64 + lane);
        }
        cnt_total += (int)__popcll(msel);
    }
    for (int i = KNN + lane; i < 128; i += 64) skey[woff + i] = ~0ULL;
    __syncthreads();

    for (int kk = 2; kk <= 128; kk <<= 1) {
        for (int jj = kk >> 1; jj >= 1; jj >>= 1) {
            const int i  = ((lane & ~(jj - 1)) << 1) | (lane & (jj - 1));
            const int ix = i | jj;
            const unsigned long long a = skey[woff + i];
            const unsigned long long b = skey[woff + ix];
            const bool up = ((i & kk) == 0);
            if ((a > b) == up) { skey[woff + i] = b; skey[woff + ix] = a; }
            __syncthreads();
        }
    }

    if (lane < KNN) {
        const int idx = (int)(unsigned)skey[woff + lane];
        nbr[t * KNN + lane] = idx;
        Aadj[(size_t)t * 512 + (idx & 511)] = (_Float16)1.0f;
    }
    if (lane + 64 < KNN) {
        const int idx = (int)(unsigned)skey[woff + lane + 64];
        nbr[t * KNN + lane + 64] = idx;
        Aadj[(size_t)t * 512 + (idx & 511)] = (_Float16)1.0f;
    }
}

// ---------------------------------------------------------------------------
// prop6: gather-average for conv1 (6 features) — cheap, kept as f32 gather.
// ---------------------------------------------------------------------------
__global__ __launch_bounds__(256) void prop6(const float* __restrict__ hin,
                                             const int* __restrict__ nbr,
                                             float* __restrict__ hout) {
    const int t = blockIdx.x * 256 + threadIdx.x;
    if (t >= N) return;
    const int* nb = nbr + t * KNN;
    float a0=0.f,a1=0.f,a2=0.f,a3=0.f,a4=0.f,a5=0.f;
    for (int i = 0; i < KNN; i += 4) {
        const int4 s4 = *(const int4*)(nb + i);
        {   const float* r = hin + (size_t)s4.x * F0;
            a0+=r[0]; a1+=r[1]; a2+=r[2]; a3+=r[3]; a4+=r[4]; a5+=r[5]; }
        {   const float* r = hin + (size_t)s4.y * F0;
            a0+=r[0]; a1+=r[1]; a2+=r[2]; a3+=r[3]; a4+=r[4]; a5+=r[5]; }
        {   const float* r = hin + (size_t)s4.z * F0;
            a0+=r[0]; a1+=r[1]; a2+=r[2]; a3+=r[3]; a4+=r[4]; a5+=r[5]; }
        {   const float* r = hin + (size_t)s4.w * F0;
            a0+=r[0]; a1+=r[1]; a2+=r[2]; a3+=r[3]; a4+=r[4]; a5+=r[5]; }
    }
    const float inv = 1.0f / 80.0f;
    float* o = hout + (size_t)t * F0;
    o[0]=a0*inv; o[1]=a1*inv; o[2]=a2*inv; o[3]=a3*inv; o[4]=a4*inv; o[5]=a5*inv;
}

// ---------------------------------------------------------------------------
// split_kernel: H f32 [8192][128]  ->  transposed fp16 2-split
// Bout[split][g][c][n] (each [16][128][512]). Block = 64 nodes, LDS transpose.
// ---------------------------------------------------------------------------
__global__ __launch_bounds__(256) void split_kernel(const float* __restrict__ H,
                                                    _Float16* __restrict__ Bout) {
    __shared__ unsigned tt[128][67];
    const int tid = threadIdx.x;
    const int n0  = blockIdx.x * 64;
    const int g   = n0 >> 9;
    const int nl  = n0 & 511;

    #pragma unroll
    for (int q = 0; q < 8; q++) {
        const int i  = tid + q * 256;           // 2048 float4 units
        const int n  = i >> 5;
        const int c4 = (i & 31) * 4;
        const float4 v = *(const float4*)(H + ((size_t)(n0 + n)) * HID + c4);
        const float fr[4] = {v.x, v.y, v.z, v.w};
        #pragma unroll
        for (int e = 0; e < 4; e++) {
            const float f = fr[e];
            const _Float16 h1 = (_Float16)f;
            const _Float16 h2 = (_Float16)(f - (float)h1);
            tt[c4 + e][n] = ((unsigned)__builtin_bit_cast(unsigned short, h2) << 16)
                          |  (unsigned)__builtin_bit_cast(unsigned short, h1);
        }
    }
    __syncthreads();

    const int c  = tid >> 1;
    const int jh = tid & 1;
    _Float16 o1[32], o2[32];
    #pragma unroll
    for (int s = 0; s < 32; s++) {
        const unsigned u = tt[c][jh * 32 + s];
        o1[s] = __builtin_bit_cast(_Float16, (unsigned short)(u & 0xFFFFu));
        o2[s] = __builtin_bit_cast(_Float16, (unsigned short)(u >> 16));
    }
    _Float16* d1 = Bout + ((size_t)g * HID + c) * NPG + nl + jh * 32;
    _Float16* d2 = d1 + SPLIT_STRIDE;
    #pragma unroll
    for (int q = 0; q < 4; q++) {
        *(uint4*)(d1 + q * 8) = *(const uint4*)&o1[q * 8];
        *(uint4*)(d2 + q * 8) = *(const uint4*)&o2[q * 8];
    }
}

// ---------------------------------------------------------------------------
// hop_kernel v2: Y = (1/80)*A@(B1+B2), wave-per-16x16-output-tile, NO LDS in
// the main loop. Block = 256 thr = 4 waves = 4 col-tiles (one 64-col half);
// grid = 512 row-tiles x 2 halves = 1024 blocks (4 blocks/CU, 4 waves/SIMD).
// A frag identical across waves (L1 broadcast); B^T frags direct from L2.
// Epilogue stages the 16x64 tile in LDS for coalesced Y (+ EMIT fp16^T splits).
// ---------------------------------------------------------------------------
template<bool EMIT>
__global__ __launch_bounds__(256) void hop_kernel(const _Float16* __restrict__ A,
                                                  const _Float16* __restrict__ Bin,
                                                  float* __restrict__ Y,
                                                  _Float16* __restrict__ Bout) {
    __shared__ float Ct[16][68];

    const int tid  = threadIdx.x;
    const int lane = tid & 63;
    const int w    = tid >> 6;          // col-tile within this half (0..3)
    const int rt   = blockIdx.x >> 1;   // 16-row tile (0..511)
    const int h    = blockIdx.x & 1;    // column half (0..1)
    const int g    = rt >> 5;           // graph

    const int row = rt * 16 + (lane & 15);
    const int col = h * 64 + w * 16 + (lane & 15);
    const int kl  = (lane >> 4) * 8;

    const _Float16* Ap = A   + (size_t)row * 512 + kl;
    const _Float16* B0 = Bin + ((size_t)g * HID + col) * NPG + kl;
    const _Float16* B1 = B0 + SPLIT_STRIDE;

    f32x4 acc = {0.f, 0.f, 0.f, 0.f};
    #pragma unroll 8
    for (int ks = 0; ks < 16; ks++) {
        const half8 af = *(const half8*)(Ap + ks * 32);
        const half8 b0 = *(const half8*)(B0 + ks * 32);
        const half8 b1 = *(const half8*)(B1 + ks * 32);
        acc = __builtin_amdgcn_mfma_f32_16x16x32_f16(af, b0, acc, 0, 0, 0);
        acc = __builtin_amdgcn_mfma_f32_16x16x32_f16(af, b1, acc, 0, 0, 0);
    }

    // stage scaled C (C/D layout: col=lane&15, row=(lane>>4)*4+reg)
    const float inv = 1.0f / 80.0f;
    {
        const int rbase = (lane >> 4) * 4;
        const int cc    = w * 16 + (lane & 15);
        #pragma unroll
        for (int rg = 0; rg < 4; rg++)
            Ct[rbase + rg][cc] = acc[rg] * inv;
    }
    __syncthreads();

    {   // Y row-major f32, coalesced: 16 rows x 64 cols = 4 floats/thread
        const int r  = tid >> 4;
        const int c4 = (tid & 15) * 4;
        const float4 v = *(const float4*)&Ct[r][c4];
        *(float4*)(Y + ((size_t)(rt * 16 + r)) * HID + h * 64 + c4) = v;
    }

    if (EMIT) {  // write Y^T fp16 splits: thread = (col 0..63, n-quad 0..3)
        const int cl = tid >> 2;
        const int nq = tid & 3;
        _Float16 o1[4], o2[4];
        #pragma unroll
        for (int i = 0; i < 4; i++) {
            const float v = Ct[nq * 4 + i][cl];
            o1[i] = (_Float16)v;
            o2[i] = (_Float16)(v - (float)o1[i]);
        }
        const int nl0 = (rt * 16) & 511;
        _Float16* d1 = Bout + ((size_t)g * HID + h * 64 + cl) * NPG + nl0 + nq * 4;
        _Float16* d2 = d1 + SPLIT_STRIDE;
        *(uint2*)d1 = *(const uint2*)o1;
        *(uint2*)d2 = *(const uint2*)o2;
    }
}

// ---------------------------------------------------------------------------
// Fused TAGConv combine as LDS-tiled GEMM (16 rows x 128 cols per block)
// + fused partial mean/max pool.
// ---------------------------------------------------------------------------
template<int K>
__global__ __launch_bounds__(256) void combine_kernel(const float* __restrict__ X,
                                                      const float* __restrict__ Y1,
                                                      const float* __restrict__ Y2,
                                                      const float* __restrict__ W,
                                                      const float* __restrict__ bias,
                                                      float* __restrict__ out,
                                                      float* __restrict__ psum,
                                                      float* __restrict__ pmax) {
    __shared__ float xs[3][RPB * K];
    const int tid  = threadIdx.x;
    const int row0 = blockIdx.x * RPB;

    {
        const float* s0 = X  + (size_t)row0 * K;
        const float* s1 = Y1 + (size_t)row0 * K;
        const float* s2 = Y2 + (size_t)row0 * K;
        if constexpr ((K & 3) == 0) {
            constexpr int NV = RPB * K / 4;
            for (int i = tid; i < NV; i += 256) ((float4*)xs[0])[i] = ((const float4*)s0)[i];
            for (int i = tid; i < NV; i += 256) ((float4*)xs[1])[i] = ((const float4*)s1)[i];
            for (int i = tid; i < NV; i += 256) ((float4*)xs[2])[i] = ((const float4*)s2)[i];
        } else {
            for (int i = tid; i < RPB * K; i += 256) xs[0][i] = s0[i];
            for (int i = tid; i < RPB * K; i += 256) xs[1][i] = s1[i];
            for (int i = tid; i < RPB * K; i += 256) xs[2][i] = s2[i];
        }
    }
    __syncthreads();

    const int c  = tid & 127;
    const int r0 = (tid >> 7) * 8;      // 0 or 8

    float acc[8];
    #pragma unroll
    for (int r = 0; r < 8; r++) acc[r] = 0.0f;

    #pragma unroll
    for (int s = 0; s < 3; s++) {
        const float* __restrict__ Ws   = W + (size_t)s * K * HID;
        const float* __restrict__ xseg = xs[s] + r0 * K;
        for (int k = 0; k < K; k += 2) {
            const float w0 = Ws[(size_t)k * HID + c];
            const float w1 = Ws[(size_t)(k + 1) * HID + c];
            #pragma unroll
            for (int r = 0; r < 8; r++)
                acc[r] += xseg[r * K + k] * w0 + xseg[r * K + k + 1] * w1;
        }
    }

    const float bb = bias[c];
    float sum8 = 0.0f, mx8 = -3.402823e38f;
    #pragma unroll
    for (int r = 0; r < 8; r++) {
        const float v = leaky(acc[r] + bb);
        out[(size_t)(row0 + r0 + r) * HID + c] = v;
        sum8 += v;
        mx8 = fmaxf(mx8, v);
    }

    __shared__ float ssum[128], smx[128];
    if (r0) { ssum[c] = sum8; smx[c] = mx8; }
    __syncthreads();
    if (!r0) {
        psum[(size_t)blockIdx.x * HID + c] = sum8 + ssum[c];
        pmax[(size_t)blockIdx.x * HID + c] = fmaxf(mx8, smx[c]);
    }
}

// ---------------------------------------------------------------------------
__global__ __launch_bounds__(128) void pool2_kernel(const float* __restrict__ psum,
                                                    const float* __restrict__ pmax,
                                                    float* __restrict__ g, int conv) {
    const int gr = blockIdx.x;
    const int c  = threadIdx.x;
    float s = 0.0f, m = -3.402823e38f;
    const float* ps = psum + (size_t)gr * BPGR * HID + c;
    const float* pm = pmax + (size_t)gr * BPGR * HID + c;
    #pragma unroll 8
    for (int b = 0; b < BPGR; b++) {
        s += ps[b * HID];
        m = fmaxf(m, pm[b * HID]);
    }
    float* grow = g + (size_t)gr * H6 + conv * 256;
    grow[c]       = s * (1.0f / 512.0f);
    grow[128 + c] = m;
}

// ---------------------------------------------------------------------------
template<bool BN>
__global__ __launch_bounds__(256) void lin_kernel(const float* __restrict__ gin,
                                                  const float* __restrict__ W,
                                                  const float* __restrict__ bias,
                                                  float* __restrict__ gout,
                                                  const float* __restrict__ gamma,
                                                  const float* __restrict__ beta,
                                                  const float* __restrict__ mean,
                                                  const float* __restrict__ var) {
    const int r   = blockIdx.x / 6;
    const int cc  = blockIdx.x % 6;
    const int tid = threadIdx.x;

    __shared__ float gs[H6];
    for (int k = tid; k < H6; k += 256) {
        float v = gin[(size_t)r * H6 + k];
        if (BN) v = (v - mean[k]) * (1.0f / sqrtf(var[k] + 1e-5f)) * gamma[k] + beta[k];
        gs[k] = v;
    }
    __syncthreads();

    const int c  = cc * 128 + (tid & 127);
    const int kh = tid >> 7;
    const int kb = kh * 384;
    float a0=0.f,a1=0.f,a2=0.f,a3=0.f;
    for (int k = kb; k < kb + 384; k += 4) {
        a0 += gs[k]     * W[(size_t)(k)     * H6 + c];
        a1 += gs[k + 1] * W[(size_t)(k + 1) * H6 + c];
        a2 += gs[k + 2] * W[(size_t)(k + 2) * H6 + c];
        a3 += gs[k + 3] * W[(size_t)(k + 3) * H6 + c];
    }
    __shared__ float part[256];
    part[tid] = (a0 + a1) + (a2 + a3);
    __syncthreads();
    if (kh == 0) {
        const float v = part[tid] + part[tid + 128] + bias[c];
        gout[(size_t)r * H6 + c] = leaky(v);
    }
}

__global__ void out_kernel(const float* __restrict__ gin,
                           const float* __restrict__ W,
                           const float* __restrict__ bias,
                           float* __restrict__ out) {
    const int tid = threadIdx.x;
    __shared__ float part[192];
    if (tid < 192) {
        const int q  = tid >> 2;        // 0..47
        const int r  = q / 3, c = q % 3;
        const int kq = tid & 3;
        float acc = 0.0f;
        for (int k = kq * 192; k < kq * 192 + 192; k++)
            acc += gin[(size_t)r * H6 + k] * W[(size_t)k * 3 + c];
        part[tid] = acc;
    }
    __syncthreads();
    if (tid < 48) {
        const int r = tid / 3, c = tid % 3;
        out[r * 3 + c] = part[tid*4] + part[tid*4+1] + part[tid*4+2] + part[tid*4+3] + bias[c];
    }
}

// ---------------------------------------------------------------------------
extern "C" void kernel_launch(void* const* d_in, const int* in_sizes, int n_in,
                              void* d_out, int out_size, void* d_ws, size_t ws_size,
                              hipStream_t stream) {
    const float* x        = (const float*)d_in[0];
    const float* conv1_w  = (const float*)d_in[2];
    const float* conv1_b  = (const float*)d_in[3];
    const float* conv2_w  = (const float*)d_in[4];
    const float* conv2_b  = (const float*)d_in[5];
    const float* conv3_w  = (const float*)d_in[6];
    const float* conv3_b  = (const float*)d_in[7];
    const float* bn_gamma = (const float*)d_in[8];
    const float* bn_beta  = (const float*)d_in[9];
    const float* bn_mean  = (const float*)d_in[10];
    const float* bn_var   = (const float*)d_in[11];
    const float* lin_w    = (const float*)d_in[12];
    const float* lin_b    = (const float*)d_in[13];
    const float* out_w    = (const float*)d_in[14];
    const float* out_b    = (const float*)d_in[15];

    char* ws = (char*)d_ws;
    size_t off = 0;
    auto alloc = [&](size_t bytes) {
        void* p = ws + off;
        off += (bytes + 255) & ~(size_t)255;
        return p;
    };
    int*      nbr  = (int*)      alloc((size_t)N * KNN * 4);
    float*    y6a  = (float*)    alloc((size_t)N * F0 * 4);
    float*    y6b  = (float*)    alloc((size_t)N * F0 * 4);
    float*    hA   = (float*)    alloc((size_t)N * HID * 4);
    float*    hB   = (float*)    alloc((size_t)N * HID * 4);
    float*    y1   = (float*)    alloc((size_t)N * HID * 4);
    float*    y2   = (float*)    alloc((size_t)N * HID * 4);
    float*    ga   = (float*)    alloc((size_t)NG * H6 * 4);
    float*    gb   = (float*)    alloc((size_t)NG * H6 * 4);
    float*    psum = (float*)    alloc((size_t)(N / RPB) * HID * 4);
    float*    pmax = (float*)    alloc((size_t)(N / RPB) * HID * 4);
    _Float16* Aadj = (_Float16*) alloc((size_t)N * NPG * 2);          // 8 MB
    _Float16* Sa   = (_Float16*) alloc(2 * SPLIT_STRIDE * 2);         // 4 MB
    _Float16* Sb   = (_Float16*) alloc(2 * SPLIT_STRIDE * 2);         // 4 MB

    knn_kernel<<<N / 4, 256, 0, stream>>>(x, nbr, Aadj);

    // conv1 (K=6): f32 gather path
    prop6<<<N / 256, 256, 0, stream>>>(x, nbr, y6a);
    prop6<<<N / 256, 256, 0, stream>>>(y6a, nbr, y6b);
    combine_kernel<6><<<N / RPB, 256, 0, stream>>>(x, y6a, y6b, conv1_w, conv1_b, hA, psum, pmax);
    pool2_kernel<<<NG, 128, 0, stream>>>(psum, pmax, ga, 0);

    // conv2 (K=128): MFMA hops
    split_kernel<<<N / 64, 256, 0, stream>>>(hA, Sa);
    hop_kernel<true ><<<N / 16 * 2, 256, 0, stream>>>(Aadj, Sa, y1, Sb);
    hop_kernel<false><<<N / 16 * 2, 256, 0, stream>>>(Aadj, Sb, y2, nullptr);
    combine_kernel<128><<<N / RPB, 256, 0, stream>>>(hA, y1, y2, conv2_w, conv2_b, hB, psum, pmax);
    pool2_kernel<<<NG, 128, 0, stream>>>(psum, pmax, ga, 1);

    // conv3 (K=128): MFMA hops
    split_kernel<<<N / 64, 256, 0, stream>>>(hB, Sa);
    hop_kernel<true ><<<N / 16 * 2, 256, 0, stream>>>(Aadj, Sa, y1, Sb);
    hop_kernel<false><<<N / 16 * 2, 256, 0, stream>>>(Aadj, Sb, y2, nullptr);
    combine_kernel<128><<<N / RPB, 256, 0, stream>>>(hB, y1, y2, conv3_w, conv3_b, hA, psum, pmax);
    pool2_kernel<<<NG, 128, 0, stream>>>(psum, pmax, ga, 2);

    // head (BN fused into first layer's staging)
    lin_kernel<true ><<<96, 256, 0, stream>>>(ga, lin_w + 0 * H6 * H6, lin_b + 0 * H6, gb,
                                              bn_gamma, bn_beta, bn_mean, bn_var);
    lin_kernel<false><<<96, 256, 0, stream>>>(gb, lin_w + 1 * H6 * H6, lin_b + 1 * H6, ga,
                                              nullptr, nullptr, nullptr, nullptr);
    lin_kernel<false><<<96, 256, 0, stream>>>(ga, lin_w + 2 * H6 * H6, lin_b + 2 * H6, gb,
                                              nullptr, nullptr, nullptr, nullptr);
    lin_kernel<false><<<96, 256, 0, stream>>>(gb, lin_w + 3 * H6 * H6, lin_b + 3 * H6, ga,
                                              nullptr, nullptr, nullptr, nullptr);
    lin_kernel<false><<<96, 256, 0, stream>>>(ga, lin_w + 4 * H6 * H6, lin_b + 4 * H6, gb,
                                              nullptr, nullptr, nullptr, nullptr);
    out_kernel<<<1, 256, 0, stream>>>(gb, out_w, out_b, (float*)d_out);
}

// Round 7
// 310.403 us; speedup vs baseline: 1.0774x; 1.0774x over previous
//
#include <hip/hip_runtime.h>

constexpr int N    = 8192;
constexpr int NPG  = 512;   // nodes per graph
constexpr int NG   = 16;
constexpr int KNN  = 80;
constexpr int F0   = 6;
constexpr int HID  = 128;
constexpr int H6   = 768;
constexpr int RPB  = 16;    // rows per combine block
constexpr int BPGR = NPG / RPB;  // combine blocks per graph = 32

__device__ __forceinline__ float leaky(float v) { return v > 0.0f ? v : 0.01f * v; }

__device__ __forceinline__ int lanes_below(unsigned long long m) {
    return __builtin_amdgcn_mbcnt_hi((unsigned)(m >> 32),
           __builtin_amdgcn_mbcnt_lo((unsigned)m, 0));
}

// wave-sum of a per-lane count in [0,8] via 4 ballots (result uniform)
__device__ __forceinline__ int wave_count_sum(int c) {
    int total = 0;
    #pragma unroll
    for (int b = 0; b < 4; b++)
        total += (int)__popcll(__ballot((c >> b) & 1)) << b;
    return total;
}

// ---------------------------------------------------------------------------
// KNN, wave-per-target (see R2 notes): exact rank-79 threshold via 32-step
// binary search on monotonic-mapped d2, tie-break by node order, 128-elem
// bitonic sort for output order.
// ---------------------------------------------------------------------------
__global__ __launch_bounds__(256) void knn_kernel(const float* __restrict__ x,
                                                  int* __restrict__ nbr) {
    constexpr int BPG = 128;               // blocks per graph (4 targets each)
    const int tid  = threadIdx.x;
    const int lane = tid & 63;
    const int wv   = tid >> 6;
    const int base = (blockIdx.x / BPG) << 9;
    const int t    = base + (blockIdx.x & (BPG - 1)) * 4 + wv;
    const int tl   = t - base;

    __shared__ float px[512], py[512], pz[512], pw[512];
    __shared__ unsigned long long skey[4 * 128];

    for (int j = tid; j < 512; j += 256) {
        const float* row = x + (size_t)(base + j) * F0;
        const float2 ra = *(const float2*)(row);
        const float2 rb = *(const float2*)(row + 2);
        px[j] = ra.x; py[j] = ra.y; pz[j] = rb.x; pw[j] = rb.y;
    }
    __syncthreads();

    const float tx = px[tl], ty = py[tl], tz = pz[tl], tw = pw[tl];
    const float sqt = tx*tx + ty*ty + tz*tz + tw*tw;

    unsigned d2m[8];
    #pragma unroll
    for (int j = 0; j < 8; j++) {
        const int node = j * 64 + lane;
        const float jx = px[node], jy = py[node], jz = pz[node], jw = pw[node];
        const float sqj = jx*jx + jy*jy + jz*jz + jw*jw;
        const float dot = tx*jx + ty*jy + tz*jz + tw*jw;
        const float d2  = sqt + sqj - 2.0f * dot;
        unsigned u = __float_as_uint(d2);
        u = (u & 0x80000000u) ? ~u : (u | 0x80000000u);   // monotonic map
        d2m[j] = (node == tl) ? 0xFFFFFFFFu : u;          // exclude self
    }

    unsigned V = 0;
    for (int b = 31; b >= 0; --b) {
        const unsigned test = V | (1u << b);
        int c = 0;
        #pragma unroll
        for (int j = 0; j < 8; j++) c += (d2m[j] < test) ? 1 : 0;
        if (wave_count_sum(c) < KNN) V = test;
    }

    int c = 0;
    #pragma unroll
    for (int j = 0; j < 8; j++) c += (d2m[j] < V) ? 1 : 0;
    const int n_lt = wave_count_sum(c);
    const int need = KNN - n_lt;

    const int woff = wv * 128;
    int cnt_total = 0, taken = 0;
    #pragma unroll
    for (int j = 0; j < 8; j++) {
        const bool lt = d2m[j] < V;
        const bool eq = d2m[j] == V;
        const unsigned long long meq = __ballot(eq);
        const bool sel = lt || (eq && (taken + lanes_below(meq)) < need);
        taken += (int)__popcll(meq);
        const unsigned long long msel = __ballot(sel);
        if (sel) {
            const int pos = cnt_total + lanes_below(msel);
            skey[woff + pos] = ((unsigned long long)d2m[j] << 32)
                             | (unsigned)(base + j * 64 + lane);
        }
        cnt_total += (int)__popcll(msel);
    }
    for (int i = KNN + lane; i < 128; i += 64) skey[woff + i] = ~0ULL;
    __syncthreads();

    for (int kk = 2; kk <= 128; kk <<= 1) {
        for (int jj = kk >> 1; jj >= 1; jj >>= 1) {
            const int i  = ((lane & ~(jj - 1)) << 1) | (lane & (jj - 1));
            const int ix = i | jj;
            const unsigned long long a = skey[woff + i];
            const unsigned long long b = skey[woff + ix];
            const bool up = ((i & kk) == 0);
            if ((a > b) == up) { skey[woff + i] = b; skey[woff + ix] = a; }
            __syncthreads();
        }
    }

    if (lane < KNN)      nbr[t * KNN + lane]      = (int)(unsigned)skey[woff + lane];
    if (lane + 64 < KNN) nbr[t * KNN + lane + 64] = (int)(unsigned)skey[woff + lane + 64];
}

// ---------------------------------------------------------------------------
// conv1 fully fused: one block per graph. Stage x (512x6) in LDS; 2 LDS-gather
// hops; combine with W in registers (18 coeffs/thread); write h + pooled
// conv1 slice of ga directly. Replaces prop6 x2 + combine<6> + pool2.
// ---------------------------------------------------------------------------
__global__ __launch_bounds__(256) void conv1_fused(const float* __restrict__ x,
                                                   const int* __restrict__ nbr,
                                                   const float* __restrict__ W,   // (3,6,128)
                                                   const float* __restrict__ bias,
                                                   float* __restrict__ h,
                                                   float* __restrict__ ga) {
    __shared__ float xs[512][F0], y1s[512][F0], y2s[512][F0];
    __shared__ float ssum[128], smx[128];
    const int gr   = blockIdx.x;
    const int base = gr << 9;
    const int tid  = threadIdx.x;

    for (int i = tid; i < 512 * F0; i += 256) ((float*)xs)[i] = x[(size_t)base * F0 + i];
    __syncthreads();

    // hop1: y1 = (1/80) A x
    for (int r = tid; r < 512; r += 256) {
        const int* nb = nbr + (size_t)(base + r) * KNN;
        float a0=0.f,a1=0.f,a2=0.f,a3=0.f,a4=0.f,a5=0.f;
        for (int i = 0; i < KNN; i += 4) {
            const int4 q = *(const int4*)(nb + i);
            const int s0=q.x&511, s1=q.y&511, s2=q.z&511, s3=q.w&511;
            a0 += (xs[s0][0]+xs[s1][0]) + (xs[s2][0]+xs[s3][0]);
            a1 += (xs[s0][1]+xs[s1][1]) + (xs[s2][1]+xs[s3][1]);
            a2 += (xs[s0][2]+xs[s1][2]) + (xs[s2][2]+xs[s3][2]);
            a3 += (xs[s0][3]+xs[s1][3]) + (xs[s2][3]+xs[s3][3]);
            a4 += (xs[s0][4]+xs[s1][4]) + (xs[s2][4]+xs[s3][4]);
            a5 += (xs[s0][5]+xs[s1][5]) + (xs[s2][5]+xs[s3][5]);
        }
        const float inv = 1.0f / 80.0f;
        y1s[r][0]=a0*inv; y1s[r][1]=a1*inv; y1s[r][2]=a2*inv;
        y1s[r][3]=a3*inv; y1s[r][4]=a4*inv; y1s[r][5]=a5*inv;
    }
    __syncthreads();

    // hop2: y2 = (1/80) A y1
    for (int r = tid; r < 512; r += 256) {
        const int* nb = nbr + (size_t)(base + r) * KNN;
        float a0=0.f,a1=0.f,a2=0.f,a3=0.f,a4=0.f,a5=0.f;
        for (int i = 0; i < KNN; i += 4) {
            const int4 q = *(const int4*)(nb + i);
            const int s0=q.x&511, s1=q.y&511, s2=q.z&511, s3=q.w&511;
            a0 += (y1s[s0][0]+y1s[s1][0]) + (y1s[s2][0]+y1s[s3][0]);
            a1 += (y1s[s0][1]+y1s[s1][1]) + (y1s[s2][1]+y1s[s3][1]);
            a2 += (y1s[s0][2]+y1s[s1][2]) + (y1s[s2][2]+y1s[s3][2]);
            a3 += (y1s[s0][3]+y1s[s1][3]) + (y1s[s2][3]+y1s[s3][3]);
            a4 += (y1s[s0][4]+y1s[s1][4]) + (y1s[s2][4]+y1s[s3][4]);
            a5 += (y1s[s0][5]+y1s[s1][5]) + (y1s[s2][5]+y1s[s3][5]);
        }
        const float inv = 1.0f / 80.0f;
        y2s[r][0]=a0*inv; y2s[r][1]=a1*inv; y2s[r][2]=a2*inv;
        y2s[r][3]=a3*inv; y2s[r][4]=a4*inv; y2s[r][5]=a5*inv;
    }
    __syncthreads();

    // combine + pool: thread = (col c, row-half rh of 256 rows)
    const int c  = tid & 127;
    const int rh = tid >> 7;
    float w0[F0], w1[F0], w2[F0];
    #pragma unroll
    for (int f = 0; f < F0; f++) {
        w0[f] = W[f * HID + c];
        w1[f] = W[(F0 + f) * HID + c];
        w2[f] = W[(2 * F0 + f) * HID + c];
    }
    const float bb = bias[c];
    float psumv = 0.0f, pmaxv = -3.402823e38f;
    for (int r = rh * 256; r < rh * 256 + 256; r++) {
        float acc = bb;
        #pragma unroll
        for (int f = 0; f < F0; f++)
            acc += xs[r][f] * w0[f] + y1s[r][f] * w1[f] + y2s[r][f] * w2[f];
        acc = leaky(acc);
        h[(size_t)(base + r) * HID + c] = acc;
        psumv += acc;
        pmaxv = fmaxf(pmaxv, acc);
    }
    if (rh) { ssum[c] = psumv; smx[c] = pmaxv; }
    __syncthreads();
    if (!rh) {
        ga[(size_t)gr * H6 + c]       = (psumv + ssum[c]) * (1.0f / 512.0f);
        ga[(size_t)gr * H6 + 128 + c] = fmaxf(pmaxv, smx[c]);
    }
}

// ---------------------------------------------------------------------------
// prop128: Y[t] = (1/80)*sum H[nbr]. 32 lanes/target (float4), 16 loads in
// flight, 256-thread blocks (8 targets), grid N/8.
// ---------------------------------------------------------------------------
__global__ __launch_bounds__(256) void prop128(const float* __restrict__ hin,
                                               const int* __restrict__ nbr,
                                               float* __restrict__ hout) {
    const int lane = threadIdx.x & 31;
    const int t    = blockIdx.x * 8 + (threadIdx.x >> 5);
    const int* nb  = nbr + t * KNN;
    float a0=0.f,a1=0.f,a2=0.f,a3=0.f;
    for (int i = 0; i < KNN; i += 16) {
        const int4 sA = *(const int4*)(nb + i);
        const int4 sB = *(const int4*)(nb + i + 4);
        const int4 sC = *(const int4*)(nb + i + 8);
        const int4 sD = *(const int4*)(nb + i + 12);
        const int idx[16] = {sA.x,sA.y,sA.z,sA.w, sB.x,sB.y,sB.z,sB.w,
                             sC.x,sC.y,sC.z,sC.w, sD.x,sD.y,sD.z,sD.w};
        float4 v[16];
        #pragma unroll
        for (int q = 0; q < 16; q++)
            v[q] = *(const float4*)(hin + (size_t)idx[q] * HID + lane * 4);
        #pragma unroll
        for (int q = 0; q < 16; q += 4) {
            a0 += (v[q].x + v[q+1].x) + (v[q+2].x + v[q+3].x);
            a1 += (v[q].y + v[q+1].y) + (v[q+2].y + v[q+3].y);
            a2 += (v[q].z + v[q+1].z) + (v[q+2].z + v[q+3].z);
            a3 += (v[q].w + v[q+1].w) + (v[q+2].w + v[q+3].w);
        }
    }
    const float inv = 1.0f / 80.0f;
    float4 r; r.x=a0*inv; r.y=a1*inv; r.z=a2*inv; r.w=a3*inv;
    *(float4*)(hout + (size_t)t * HID + lane * 4) = r;
}

// ---------------------------------------------------------------------------
// Fused TAGConv combine as LDS-tiled GEMM (16 rows x 128 cols per block)
// + fused partial mean/max pool into per-conv psum/pmax buffers.
// ---------------------------------------------------------------------------
template<int K>
__global__ __launch_bounds__(256) void combine_kernel(const float* __restrict__ X,
                                                      const float* __restrict__ Y1,
                                                      const float* __restrict__ Y2,
                                                      const float* __restrict__ W,
                                                      const float* __restrict__ bias,
                                                      float* __restrict__ out,
                                                      float* __restrict__ psum,
                                                      float* __restrict__ pmax) {
    __shared__ float xs[3][RPB * K];
    const int tid  = threadIdx.x;
    const int row0 = blockIdx.x * RPB;

    {
        const float* s0 = X  + (size_t)row0 * K;
        const float* s1 = Y1 + (size_t)row0 * K;
        const float* s2 = Y2 + (size_t)row0 * K;
        constexpr int NV = RPB * K / 4;
        for (int i = tid; i < NV; i += 256) ((float4*)xs[0])[i] = ((const float4*)s0)[i];
        for (int i = tid; i < NV; i += 256) ((float4*)xs[1])[i] = ((const float4*)s1)[i];
        for (int i = tid; i < NV; i += 256) ((float4*)xs[2])[i] = ((const float4*)s2)[i];
    }
    __syncthreads();

    const int c  = tid & 127;
    const int r0 = (tid >> 7) * 8;      // 0 or 8

    float acc[8];
    #pragma unroll
    for (int r = 0; r < 8; r++) acc[r] = 0.0f;

    #pragma unroll
    for (int s = 0; s < 3; s++) {
        const float* __restrict__ Ws   = W + (size_t)s * K * HID;
        const float* __restrict__ xseg = xs[s] + r0 * K;
        for (int k = 0; k < K; k += 2) {
            const float w0 = Ws[(size_t)k * HID + c];
            const float w1 = Ws[(size_t)(k + 1) * HID + c];
            #pragma unroll
            for (int r = 0; r < 8; r++)
                acc[r] += xseg[r * K + k] * w0 + xseg[r * K + k + 1] * w1;
        }
    }

    const float bb = bias[c];
    float sum8 = 0.0f, mx8 = -3.402823e38f;
    #pragma unroll
    for (int r = 0; r < 8; r++) {
        const float v = leaky(acc[r] + bb);
        out[(size_t)(row0 + r0 + r) * HID + c] = v;
        sum8 += v;
        mx8 = fmaxf(mx8, v);
    }

    __shared__ float ssum[128], smx[128];
    if (r0) { ssum[c] = sum8; smx[c] = mx8; }
    __syncthreads();
    if (!r0) {
        psum[(size_t)blockIdx.x * HID + c] = sum8 + ssum[c];
        pmax[(size_t)blockIdx.x * HID + c] = fmaxf(mx8, smx[c]);
    }
}

// ---------------------------------------------------------------------------
// lin0: stages gs[768] from (ga conv1 slice) + (conv2/conv3 partial pools),
// applies BN, then layer-0 GEMM. Grid = 16 rows x 6 col-chunks.
// ---------------------------------------------------------------------------
__global__ __launch_bounds__(256) void lin0_kernel(const float* __restrict__ ga,
                                                   const float* __restrict__ psum2,
                                                   const float* __restrict__ pmax2,
                                                   const float* __restrict__ psum3,
                                                   const float* __restrict__ pmax3,
                                                   const float* __restrict__ gamma,
                                                   const float* __restrict__ beta,
                                                   const float* __restrict__ mean,
                                                   const float* __restrict__ var,
                                                   const float* __restrict__ W,
                                                   const float* __restrict__ bias,
                                                   float* __restrict__ gout) {
    const int r   = blockIdx.x / 6;
    const int cc  = blockIdx.x % 6;
    const int tid = threadIdx.x;

    __shared__ float gs[H6];
    {
        const int c  = tid & 127;
        const int cv = tid >> 7;                 // 0: conv2, 1: conv3
        const float* ps = (cv ? psum3 : psum2) + (size_t)r * BPGR * HID + c;
        const float* pm = (cv ? pmax3 : pmax2) + (size_t)r * BPGR * HID + c;
        float s = 0.0f, m = -3.402823e38f;
        #pragma unroll 8
        for (int b = 0; b < BPGR; b++) { s += ps[b * HID]; m = fmaxf(m, pm[b * HID]); }
        gs[256 + cv * 256 + c]       = s * (1.0f / 512.0f);
        gs[256 + cv * 256 + 128 + c] = m;
        gs[tid] = ga[(size_t)r * H6 + tid];      // conv1 slice (256 values)
    }
    __syncthreads();
    for (int k = tid; k < H6; k += 256)
        gs[k] = (gs[k] - mean[k]) * (1.0f / sqrtf(var[k] + 1e-5f)) * gamma[k] + beta[k];
    __syncthreads();

    const int c  = cc * 128 + (tid & 127);
    const int kh = tid >> 7;
    const int kb = kh * 384;
    float a0=0.f,a1=0.f,a2=0.f,a3=0.f;
    for (int k = kb; k < kb + 384; k += 4) {
        a0 += gs[k]     * W[(size_t)(k)     * H6 + c];
        a1 += gs[k + 1] * W[(size_t)(k + 1) * H6 + c];
        a2 += gs[k + 2] * W[(size_t)(k + 2) * H6 + c];
        a3 += gs[k + 3] * W[(size_t)(k + 3) * H6 + c];
    }
    __shared__ float part[256];
    part[tid] = (a0 + a1) + (a2 + a3);
    __syncthreads();
    if (kh == 0) {
        const float v = part[tid] + part[tid + 128] + bias[c];
        gout[(size_t)r * H6 + c] = leaky(v);
    }
}

// ---------------------------------------------------------------------------
__global__ __launch_bounds__(256) void lin_kernel(const float* __restrict__ gin,
                                                  const float* __restrict__ W,
                                                  const float* __restrict__ bias,
                                                  float* __restrict__ gout) {
    const int r   = blockIdx.x / 6;
    const int cc  = blockIdx.x % 6;
    const int tid = threadIdx.x;

    __shared__ float gs[H6];
    for (int k = tid; k < H6; k += 256) gs[k] = gin[(size_t)r * H6 + k];
    __syncthreads();

    const int c  = cc * 128 + (tid & 127);
    const int kh = tid >> 7;
    const int kb = kh * 384;
    float a0=0.f,a1=0.f,a2=0.f,a3=0.f;
    for (int k = kb; k < kb + 384; k += 4) {
        a0 += gs[k]     * W[(size_t)(k)     * H6 + c];
        a1 += gs[k + 1] * W[(size_t)(k + 1) * H6 + c];
        a2 += gs[k + 2] * W[(size_t)(k + 2) * H6 + c];
        a3 += gs[k + 3] * W[(size_t)(k + 3) * H6 + c];
    }
    __shared__ float part[256];
    part[tid] = (a0 + a1) + (a2 + a3);
    __syncthreads();
    if (kh == 0) {
        const float v = part[tid] + part[tid + 128] + bias[c];
        gout[(size_t)r * H6 + c] = leaky(v);
    }
}

__global__ void out_kernel(const float* __restrict__ gin,
                           const float* __restrict__ W,
                           const float* __restrict__ bias,
                           float* __restrict__ out) {
    const int tid = threadIdx.x;
    __shared__ float part[192];
    if (tid < 192) {
        const int q  = tid >> 2;        // 0..47
        const int r  = q / 3, c = q % 3;
        const int kq = tid & 3;
        float acc = 0.0f;
        for (int k = kq * 192; k < kq * 192 + 192; k++)
            acc += gin[(size_t)r * H6 + k] * W[(size_t)k * 3 + c];
        part[tid] = acc;
    }
    __syncthreads();
    if (tid < 48) {
        const int r = tid / 3, c = tid % 3;
        out[r * 3 + c] = part[tid*4] + part[tid*4+1] + part[tid*4+2] + part[tid*4+3] + bias[c];
    }
}

// ---------------------------------------------------------------------------
extern "C" void kernel_launch(void* const* d_in, const int* in_sizes, int n_in,
                              void* d_out, int out_size, void* d_ws, size_t ws_size,
                              hipStream_t stream) {
    const float* x        = (const float*)d_in[0];
    const float* conv1_w  = (const float*)d_in[2];
    const float* conv1_b  = (const float*)d_in[3];
    const float* conv2_w  = (const float*)d_in[4];
    const float* conv2_b  = (const float*)d_in[5];
    const float* conv3_w  = (const float*)d_in[6];
    const float* conv3_b  = (const float*)d_in[7];
    const float* bn_gamma = (const float*)d_in[8];
    const float* bn_beta  = (const float*)d_in[9];
    const float* bn_mean  = (const float*)d_in[10];
    const float* bn_var   = (const float*)d_in[11];
    const float* lin_w    = (const float*)d_in[12];
    const float* lin_b    = (const float*)d_in[13];
    const float* out_w    = (const float*)d_in[14];
    const float* out_b    = (const float*)d_in[15];

    char* ws = (char*)d_ws;
    size_t off = 0;
    auto alloc = [&](size_t bytes) {
        void* p = ws + off;
        off += (bytes + 255) & ~(size_t)255;
        return p;
    };
    int*   nbr   = (int*)  alloc((size_t)N * KNN * 4);
    float* hA    = (float*)alloc((size_t)N * HID * 4);
    float* hB    = (float*)alloc((size_t)N * HID * 4);
    float* y1    = (float*)alloc((size_t)N * HID * 4);
    float* y2    = (float*)alloc((size_t)N * HID * 4);
    float* ga    = (float*)alloc((size_t)NG * H6 * 4);
    float* gb    = (float*)alloc((size_t)NG * H6 * 4);
    float* psum2 = (float*)alloc((size_t)(N / RPB) * HID * 4);
    float* pmax2 = (float*)alloc((size_t)(N / RPB) * HID * 4);
    float* psum3 = (float*)alloc((size_t)(N / RPB) * HID * 4);
    float* pmax3 = (float*)alloc((size_t)(N / RPB) * HID * 4);

    knn_kernel<<<N / 4, 256, 0, stream>>>(x, nbr);

    // conv1 (K=6): fully fused per-graph kernel (hops in LDS + combine + pool)
    conv1_fused<<<NG, 256, 0, stream>>>(x, nbr, conv1_w, conv1_b, hA, ga);

    // conv2 (K=128)
    prop128<<<N / 8, 256, 0, stream>>>(hA, nbr, y1);
    prop128<<<N / 8, 256, 0, stream>>>(y1, nbr, y2);
    combine_kernel<128><<<N / RPB, 256, 0, stream>>>(hA, y1, y2, conv2_w, conv2_b, hB, psum2, pmax2);

    // conv3 (K=128)
    prop128<<<N / 8, 256, 0, stream>>>(hB, nbr, y1);
    prop128<<<N / 8, 256, 0, stream>>>(y1, nbr, y2);
    combine_kernel<128><<<N / RPB, 256, 0, stream>>>(hB, y1, y2, conv3_w, conv3_b, hA, psum3, pmax3);

    // head: lin0 fuses pool2(conv2/3) + BN; then 4 lin layers + out
    lin0_kernel<<<96, 256, 0, stream>>>(ga, psum2, pmax2, psum3, pmax3,
                                        bn_gamma, bn_beta, bn_mean, bn_var,
                                        lin_w + 0 * H6 * H6, lin_b + 0 * H6, gb);
    lin_kernel<<<96, 256, 0, stream>>>(gb, lin_w + 1 * H6 * H6, lin_b + 1 * H6, ga);
    lin_kernel<<<96, 256, 0, stream>>>(ga, lin_w + 2 * H6 * H6, lin_b + 2 * H6, gb);
    lin_kernel<<<96, 256, 0, stream>>>(gb, lin_w + 3 * H6 * H6, lin_b + 3 * H6, ga);
    lin_kernel<<<96, 256, 0, stream>>>(ga, lin_w + 4 * H6 * H6, lin_b + 4 * H6, gb);
    out_kernel<<<1, 256, 0, stream>>>(gb, out_w, out_b, (float*)d_out);
}

// Round 8
// 265.466 us; speedup vs baseline: 1.2598x; 1.1693x over previous
//
#include <hip/hip_runtime.h>

constexpr int N    = 8192;
constexpr int NPG  = 512;   // nodes per graph
constexpr int NG   = 16;
constexpr int KNN  = 80;
constexpr int F0   = 6;
constexpr int HID  = 128;
constexpr int H6   = 768;
constexpr int RPB  = 16;    // rows per combine block
constexpr int BPGR = NPG / RPB;  // combine blocks per graph = 32

__device__ __forceinline__ float leaky(float v) { return v > 0.0f ? v : 0.01f * v; }

__device__ __forceinline__ int lanes_below(unsigned long long m) {
    return __builtin_amdgcn_mbcnt_hi((unsigned)(m >> 32),
           __builtin_amdgcn_mbcnt_lo((unsigned)m, 0));
}

// wave-sum of a per-lane count in [0,8] via 4 ballots (result uniform)
__device__ __forceinline__ int wave_count_sum(int c) {
    int total = 0;
    #pragma unroll
    for (int b = 0; b < 4; b++)
        total += (int)__popcll(__ballot((c >> b) & 1)) << b;
    return total;
}

// ---------------------------------------------------------------------------
// KNN, wave-per-target (see R2 notes): exact rank-79 threshold via 32-step
// binary search on monotonic-mapped d2, tie-break by node order, 128-elem
// bitonic sort for output order.
// ---------------------------------------------------------------------------
__global__ __launch_bounds__(256) void knn_kernel(const float* __restrict__ x,
                                                  int* __restrict__ nbr) {
    constexpr int BPG = 128;               // blocks per graph (4 targets each)
    const int tid  = threadIdx.x;
    const int lane = tid & 63;
    const int wv   = tid >> 6;
    const int base = (blockIdx.x / BPG) << 9;
    const int t    = base + (blockIdx.x & (BPG - 1)) * 4 + wv;
    const int tl   = t - base;

    __shared__ float px[512], py[512], pz[512], pw[512];
    __shared__ unsigned long long skey[4 * 128];

    for (int j = tid; j < 512; j += 256) {
        const float* row = x + (size_t)(base + j) * F0;
        const float2 ra = *(const float2*)(row);
        const float2 rb = *(const float2*)(row + 2);
        px[j] = ra.x; py[j] = ra.y; pz[j] = rb.x; pw[j] = rb.y;
    }
    __syncthreads();

    const float tx = px[tl], ty = py[tl], tz = pz[tl], tw = pw[tl];
    const float sqt = tx*tx + ty*ty + tz*tz + tw*tw;

    unsigned d2m[8];
    #pragma unroll
    for (int j = 0; j < 8; j++) {
        const int node = j * 64 + lane;
        const float jx = px[node], jy = py[node], jz = pz[node], jw = pw[node];
        const float sqj = jx*jx + jy*jy + jz*jz + jw*jw;
        const float dot = tx*jx + ty*jy + tz*jz + tw*jw;
        const float d2  = sqt + sqj - 2.0f * dot;
        unsigned u = __float_as_uint(d2);
        u = (u & 0x80000000u) ? ~u : (u | 0x80000000u);   // monotonic map
        d2m[j] = (node == tl) ? 0xFFFFFFFFu : u;          // exclude self
    }

    unsigned V = 0;
    for (int b = 31; b >= 0; --b) {
        const unsigned test = V | (1u << b);
        int c = 0;
        #pragma unroll
        for (int j = 0; j < 8; j++) c += (d2m[j] < test) ? 1 : 0;
        if (wave_count_sum(c) < KNN) V = test;
    }

    int c = 0;
    #pragma unroll
    for (int j = 0; j < 8; j++) c += (d2m[j] < V) ? 1 : 0;
    const int n_lt = wave_count_sum(c);
    const int need = KNN - n_lt;

    const int woff = wv * 128;
    int cnt_total = 0, taken = 0;
    #pragma unroll
    for (int j = 0; j < 8; j++) {
        const bool lt = d2m[j] < V;
        const bool eq = d2m[j] == V;
        const unsigned long long meq = __ballot(eq);
        const bool sel = lt || (eq && (taken + lanes_below(meq)) < need);
        taken += (int)__popcll(meq);
        const unsigned long long msel = __ballot(sel);
        if (sel) {
            const int pos = cnt_total + lanes_below(msel);
            skey[woff + pos] = ((unsigned long long)d2m[j] << 32)
                             | (unsigned)(base + j * 64 + lane);
        }
        cnt_total += (int)__popcll(msel);
    }
    for (int i = KNN + lane; i < 128; i += 64) skey[woff + i] = ~0ULL;
    __syncthreads();

    for (int kk = 2; kk <= 128; kk <<= 1) {
        for (int jj = kk >> 1; jj >= 1; jj >>= 1) {
            const int i  = ((lane & ~(jj - 1)) << 1) | (lane & (jj - 1));
            const int ix = i | jj;
            const unsigned long long a = skey[woff + i];
            const unsigned long long b = skey[woff + ix];
            const bool up = ((i & kk) == 0);
            if ((a > b) == up) { skey[woff + i] = b; skey[woff + ix] = a; }
            __syncthreads();
        }
    }

    if (lane < KNN)      nbr[t * KNN + lane]      = (int)(unsigned)skey[woff + lane];
    if (lane + 64 < KNN) nbr[t * KNN + lane + 64] = (int)(unsigned)skey[woff + lane + 64];
}

// ---------------------------------------------------------------------------
// prop6 v2: Y[t] = (1/80)*sum H[nbr], 6 feats. 8 lanes per node, 10 neighbors
// each, shuffle-reduce across the 8-lane group. Grid = 256 blocks.
// ---------------------------------------------------------------------------
__global__ __launch_bounds__(256) void prop6(const float* __restrict__ hin,
                                             const int* __restrict__ nbr,
                                             float* __restrict__ hout) {
    const int gid = blockIdx.x * 256 + threadIdx.x;
    const int t   = gid >> 3;
    const int sl  = gid & 7;
    const int* nb = nbr + t * KNN + sl * 10;

    float a[F0] = {0.f, 0.f, 0.f, 0.f, 0.f, 0.f};
    #pragma unroll
    for (int j = 0; j < 10; j++) {
        const float* r = hin + (size_t)nb[j] * F0;
        #pragma unroll
        for (int f = 0; f < F0; f++) a[f] += r[f];
    }
    #pragma unroll
    for (int off = 1; off < 8; off <<= 1)
        #pragma unroll
        for (int f = 0; f < F0; f++) a[f] += __shfl_xor(a[f], off);

    if (sl == 0) {
        const float inv = 1.0f / 80.0f;
        float* o = hout + (size_t)t * F0;
        #pragma unroll
        for (int f = 0; f < F0; f++) o[f] = a[f] * inv;
    }
}

// ---------------------------------------------------------------------------
// prop128: Y[t] = (1/80)*sum H[nbr]. 32 lanes/target (float4), 16 loads in
// flight, 256-thread blocks (8 targets), grid N/8.
// ---------------------------------------------------------------------------
__global__ __launch_bounds__(256) void prop128(const float* __restrict__ hin,
                                               const int* __restrict__ nbr,
                                               float* __restrict__ hout) {
    const int lane = threadIdx.x & 31;
    const int t    = blockIdx.x * 8 + (threadIdx.x >> 5);
    const int* nb  = nbr + t * KNN;
    float a0=0.f,a1=0.f,a2=0.f,a3=0.f;
    for (int i = 0; i < KNN; i += 16) {
        const int4 sA = *(const int4*)(nb + i);
        const int4 sB = *(const int4*)(nb + i + 4);
        const int4 sC = *(const int4*)(nb + i + 8);
        const int4 sD = *(const int4*)(nb + i + 12);
        const int idx[16] = {sA.x,sA.y,sA.z,sA.w, sB.x,sB.y,sB.z,sB.w,
                             sC.x,sC.y,sC.z,sC.w, sD.x,sD.y,sD.z,sD.w};
        float4 v[16];
        #pragma unroll
        for (int q = 0; q < 16; q++)
            v[q] = *(const float4*)(hin + (size_t)idx[q] * HID + lane * 4);
        #pragma unroll
        for (int q = 0; q < 16; q += 4) {
            a0 += (v[q].x + v[q+1].x) + (v[q+2].x + v[q+3].x);
            a1 += (v[q].y + v[q+1].y) + (v[q+2].y + v[q+3].y);
            a2 += (v[q].z + v[q+1].z) + (v[q+2].z + v[q+3].z);
            a3 += (v[q].w + v[q+1].w) + (v[q+2].w + v[q+3].w);
        }
    }
    const float inv = 1.0f / 80.0f;
    float4 r; r.x=a0*inv; r.y=a1*inv; r.z=a2*inv; r.w=a3*inv;
    *(float4*)(hout + (size_t)t * HID + lane * 4) = r;
}

// ---------------------------------------------------------------------------
// Fused TAGConv combine as LDS-tiled GEMM (16 rows x 128 cols per block)
// + fused partial mean/max pool into per-conv psum/pmax buffers.
// ---------------------------------------------------------------------------
template<int K>
__global__ __launch_bounds__(256) void combine_kernel(const float* __restrict__ X,
                                                      const float* __restrict__ Y1,
                                                      const float* __restrict__ Y2,
                                                      const float* __restrict__ W,
                                                      const float* __restrict__ bias,
                                                      float* __restrict__ out,
                                                      float* __restrict__ psum,
                                                      float* __restrict__ pmax) {
    __shared__ float xs[3][RPB * K];
    const int tid  = threadIdx.x;
    const int row0 = blockIdx.x * RPB;

    {
        const float* s0 = X  + (size_t)row0 * K;
        const float* s1 = Y1 + (size_t)row0 * K;
        const float* s2 = Y2 + (size_t)row0 * K;
        if constexpr ((K & 3) == 0) {
            constexpr int NV = RPB * K / 4;
            for (int i = tid; i < NV; i += 256) ((float4*)xs[0])[i] = ((const float4*)s0)[i];
            for (int i = tid; i < NV; i += 256) ((float4*)xs[1])[i] = ((const float4*)s1)[i];
            for (int i = tid; i < NV; i += 256) ((float4*)xs[2])[i] = ((const float4*)s2)[i];
        } else {
            for (int i = tid; i < RPB * K; i += 256) xs[0][i] = s0[i];
            for (int i = tid; i < RPB * K; i += 256) xs[1][i] = s1[i];
            for (int i = tid; i < RPB * K; i += 256) xs[2][i] = s2[i];
        }
    }
    __syncthreads();

    const int c  = tid & 127;
    const int r0 = (tid >> 7) * 8;      // 0 or 8

    float acc[8];
    #pragma unroll
    for (int r = 0; r < 8; r++) acc[r] = 0.0f;

    #pragma unroll
    for (int s = 0; s < 3; s++) {
        const float* __restrict__ Ws   = W + (size_t)s * K * HID;
        const float* __restrict__ xseg = xs[s] + r0 * K;
        for (int k = 0; k < K; k += 2) {
            const float w0 = Ws[(size_t)k * HID + c];
            const float w1 = Ws[(size_t)(k + 1) * HID + c];
            #pragma unroll
            for (int r = 0; r < 8; r++)
                acc[r] += xseg[r * K + k] * w0 + xseg[r * K + k + 1] * w1;
        }
    }

    const float bb = bias[c];
    float sum8 = 0.0f, mx8 = -3.402823e38f;
    #pragma unroll
    for (int r = 0; r < 8; r++) {
        const float v = leaky(acc[r] + bb);
        out[(size_t)(row0 + r0 + r) * HID + c] = v;
        sum8 += v;
        mx8 = fmaxf(mx8, v);
    }

    __shared__ float ssum[128], smx[128];
    if (r0) { ssum[c] = sum8; smx[c] = mx8; }
    __syncthreads();
    if (!r0) {
        psum[(size_t)blockIdx.x * HID + c] = sum8 + ssum[c];
        pmax[(size_t)blockIdx.x * HID + c] = fmaxf(mx8, smx[c]);
    }
}

// ---------------------------------------------------------------------------
// lin0: reduces all three convs' pool partials into gs[768], applies BN,
// then layer-0 GEMM. Grid = 16 rows x 6 col-chunks.
// ---------------------------------------------------------------------------
__global__ __launch_bounds__(256) void lin0_kernel(const float* __restrict__ psum1,
                                                   const float* __restrict__ pmax1,
                                                   const float* __restrict__ psum2,
                                                   const float* __restrict__ pmax2,
                                                   const float* __restrict__ psum3,
                                                   const float* __restrict__ pmax3,
                                                   const float* __restrict__ gamma,
                                                   const float* __restrict__ beta,
                                                   const float* __restrict__ mean,
                                                   const float* __restrict__ var,
                                                   const float* __restrict__ W,
                                                   const float* __restrict__ bias,
                                                   float* __restrict__ gout) {
    const int r   = blockIdx.x / 6;
    const int cc  = blockIdx.x % 6;
    const int tid = threadIdx.x;

    __shared__ float gs[H6];
    {   // task 1: conv1 (tid>>7==0) or conv2 (tid>>7==1)
        const int cv = tid >> 7;
        const int c  = tid & 127;
        const float* ps = (cv ? psum2 : psum1) + (size_t)r * BPGR * HID + c;
        const float* pm = (cv ? pmax2 : pmax1) + (size_t)r * BPGR * HID + c;
        float s = 0.0f, m = -3.402823e38f;
        #pragma unroll 8
        for (int b = 0; b < BPGR; b++) { s += ps[b * HID]; m = fmaxf(m, pm[b * HID]); }
        gs[cv * 256 + c]       = s * (1.0f / 512.0f);
        gs[cv * 256 + 128 + c] = m;
    }
    if (tid < 128) {  // task 2: conv3
        const float* ps = psum3 + (size_t)r * BPGR * HID + tid;
        const float* pm = pmax3 + (size_t)r * BPGR * HID + tid;
        float s = 0.0f, m = -3.402823e38f;
        #pragma unroll 8
        for (int b = 0; b < BPGR; b++) { s += ps[b * HID]; m = fmaxf(m, pm[b * HID]); }
        gs[512 + tid]       = s * (1.0f / 512.0f);
        gs[512 + 128 + tid] = m;
    }
    __syncthreads();
    for (int k = tid; k < H6; k += 256)
        gs[k] = (gs[k] - mean[k]) * (1.0f / sqrtf(var[k] + 1e-5f)) * gamma[k] + beta[k];
    __syncthreads();

    const int c  = cc * 128 + (tid & 127);
    const int kh = tid >> 7;
    const int kb = kh * 384;
    float a0=0.f,a1=0.f,a2=0.f,a3=0.f;
    for (int k = kb; k < kb + 384; k += 4) {
        a0 += gs[k]     * W[(size_t)(k)     * H6 + c];
        a1 += gs[k + 1] * W[(size_t)(k + 1) * H6 + c];
        a2 += gs[k + 2] * W[(size_t)(k + 2) * H6 + c];
        a3 += gs[k + 3] * W[(size_t)(k + 3) * H6 + c];
    }
    __shared__ float part[256];
    part[tid] = (a0 + a1) + (a2 + a3);
    __syncthreads();
    if (kh == 0) {
        const float v = part[tid] + part[tid + 128] + bias[c];
        gout[(size_t)r * H6 + c] = leaky(v);
    }
}

// ---------------------------------------------------------------------------
__global__ __launch_bounds__(256) void lin_kernel(const float* __restrict__ gin,
                                                  const float* __restrict__ W,
                                                  const float* __restrict__ bias,
                                                  float* __restrict__ gout) {
    const int r   = blockIdx.x / 6;
    const int cc  = blockIdx.x % 6;
    const int tid = threadIdx.x;

    __shared__ float gs[H6];
    for (int k = tid; k < H6; k += 256) gs[k] = gin[(size_t)r * H6 + k];
    __syncthreads();

    const int c  = cc * 128 + (tid & 127);
    const int kh = tid >> 7;
    const int kb = kh * 384;
    float a0=0.f,a1=0.f,a2=0.f,a3=0.f;
    for (int k = kb; k < kb + 384; k += 4) {
        a0 += gs[k]     * W[(size_t)(k)     * H6 + c];
        a1 += gs[k + 1] * W[(size_t)(k + 1) * H6 + c];
        a2 += gs[k + 2] * W[(size_t)(k + 2) * H6 + c];
        a3 += gs[k + 3] * W[(size_t)(k + 3) * H6 + c];
    }
    __shared__ float part[256];
    part[tid] = (a0 + a1) + (a2 + a3);
    __syncthreads();
    if (kh == 0) {
        const float v = part[tid] + part[tid + 128] + bias[c];
        gout[(size_t)r * H6 + c] = leaky(v);
    }
}

__global__ void out_kernel(const float* __restrict__ gin,
                           const float* __restrict__ W,
                           const float* __restrict__ bias,
                           float* __restrict__ out) {
    const int tid = threadIdx.x;
    __shared__ float part[192];
    if (tid < 192) {
        const int q  = tid >> 2;        // 0..47
        const int r  = q / 3, c = q % 3;
        const int kq = tid & 3;
        float acc = 0.0f;
        for (int k = kq * 192; k < kq * 192 + 192; k++)
            acc += gin[(size_t)r * H6 + k] * W[(size_t)k * 3 + c];
        part[tid] = acc;
    }
    __syncthreads();
    if (tid < 48) {
        const int r = tid / 3, c = tid % 3;
        out[r * 3 + c] = part[tid*4] + part[tid*4+1] + part[tid*4+2] + part[tid*4+3] + bias[c];
    }
}

// ---------------------------------------------------------------------------
extern "C" void kernel_launch(void* const* d_in, const int* in_sizes, int n_in,
                              void* d_out, int out_size, void* d_ws, size_t ws_size,
                              hipStream_t stream) {
    const float* x        = (const float*)d_in[0];
    const float* conv1_w  = (const float*)d_in[2];
    const float* conv1_b  = (const float*)d_in[3];
    const float* conv2_w  = (const float*)d_in[4];
    const float* conv2_b  = (const float*)d_in[5];
    const float* conv3_w  = (const float*)d_in[6];
    const float* conv3_b  = (const float*)d_in[7];
    const float* bn_gamma = (const float*)d_in[8];
    const float* bn_beta  = (const float*)d_in[9];
    const float* bn_mean  = (const float*)d_in[10];
    const float* bn_var   = (const float*)d_in[11];
    const float* lin_w    = (const float*)d_in[12];
    const float* lin_b    = (const float*)d_in[13];
    const float* out_w    = (const float*)d_in[14];
    const float* out_b    = (const float*)d_in[15];

    char* ws = (char*)d_ws;
    size_t off = 0;
    auto alloc = [&](size_t bytes) {
        void* p = ws + off;
        off += (bytes + 255) & ~(size_t)255;
        return p;
    };
    int*   nbr   = (int*)  alloc((size_t)N * KNN * 4);
    float* y6a   = (float*)alloc((size_t)N * F0 * 4);
    float* y6b   = (float*)alloc((size_t)N * F0 * 4);
    float* hA    = (float*)alloc((size_t)N * HID * 4);
    float* hB    = (float*)alloc((size_t)N * HID * 4);
    float* y1    = (float*)alloc((size_t)N * HID * 4);
    float* y2    = (float*)alloc((size_t)N * HID * 4);
    float* ga    = (float*)alloc((size_t)NG * H6 * 4);
    float* gb    = (float*)alloc((size_t)NG * H6 * 4);
    float* psum1 = (float*)alloc((size_t)(N / RPB) * HID * 4);
    float* pmax1 = (float*)alloc((size_t)(N / RPB) * HID * 4);
    float* psum2 = (float*)alloc((size_t)(N / RPB) * HID * 4);
    float* pmax2 = (float*)alloc((size_t)(N / RPB) * HID * 4);
    float* psum3 = (float*)alloc((size_t)(N / RPB) * HID * 4);
    float* pmax3 = (float*)alloc((size_t)(N / RPB) * HID * 4);

    knn_kernel<<<N / 4, 256, 0, stream>>>(x, nbr);

    // conv1 (K=6): distributed kernels (R7's 16-block fusion was a 60 µs trap)
    prop6<<<N * 8 / 256, 256, 0, stream>>>(x, nbr, y6a);
    prop6<<<N * 8 / 256, 256, 0, stream>>>(y6a, nbr, y6b);
    combine_kernel<6><<<N / RPB, 256, 0, stream>>>(x, y6a, y6b, conv1_w, conv1_b, hA, psum1, pmax1);

    // conv2 (K=128)
    prop128<<<N / 8, 256, 0, stream>>>(hA, nbr, y1);
    prop128<<<N / 8, 256, 0, stream>>>(y1, nbr, y2);
    combine_kernel<128><<<N / RPB, 256, 0, stream>>>(hA, y1, y2, conv2_w, conv2_b, hB, psum2, pmax2);

    // conv3 (K=128)
    prop128<<<N / 8, 256, 0, stream>>>(hB, nbr, y1);
    prop128<<<N / 8, 256, 0, stream>>>(y1, nbr, y2);
    combine_kernel<128><<<N / RPB, 256, 0, stream>>>(hB, y1, y2, conv3_w, conv3_b, hA, psum3, pmax3);

    // head: lin0 fuses pool2(all convs) + BN; then 4 lin layers + out
    lin0_kernel<<<96, 256, 0, stream>>>(psum1, pmax1, psum2, pmax2, psum3, pmax3,
                                        bn_gamma, bn_beta, bn_mean, bn_var,
                                        lin_w + 0 * H6 * H6, lin_b + 0 * H6, gb);
    lin_kernel<<<96, 256, 0, stream>>>(gb, lin_w + 1 * H6 * H6, lin_b + 1 * H6, ga);
    lin_kernel<<<96, 256, 0, stream>>>(ga, lin_w + 2 * H6 * H6, lin_b + 2 * H6, gb);
    lin_kernel<<<96, 256, 0, stream>>>(gb, lin_w + 3 * H6 * H6, lin_b + 3 * H6, ga);
    lin_kernel<<<96, 256, 0, stream>>>(ga, lin_w + 4 * H6 * H6, lin_b + 4 * H6, gb);
    out_kernel<<<1, 256, 0, stream>>>(gb, out_w, out_b, (float*)d_out);
}